// Round 2
// baseline (443.734 us; speedup 1.0000x reference)
//
#include <hip/hip_runtime.h>
#include <stdint.h>

#define CC 256
#define HH 80
#define WW 80
#define PP 6400          // 80*80
#define GG 16
#define GNCNT (16*6400)  // elements per (n,group): 16 channels * 6400

using frag_ab = __attribute__((ext_vector_type(8))) short;   // 8 bf16
using frag_cd = __attribute__((ext_vector_type(4))) float;   // 4 fp32
typedef unsigned short u16;

__device__ __forceinline__ float b2f(u16 u) {
    union { float f; uint32_t i; } v; v.i = ((uint32_t)u) << 16; return v.f;
}
__device__ __forceinline__ u16 f2b(float f) {
    uint32_t x = __float_as_uint(f);
    return (u16)((x + 0x7fffu + ((x >> 16) & 1u)) >> 16);  // RNE
}
__device__ __forceinline__ float sigf(float x) { return 1.f / (1.f + __expf(-x)); }

// fp32 -> bf16 conversion, 4 elements/thread
__global__ __launch_bounds__(256) void cvt_kernel(const float* __restrict__ src,
                                                  u16* __restrict__ dst, int n4) {
    int i = blockIdx.x * 256 + threadIdx.x;
    if (i < n4) {
        float4 v = ((const float4*)src)[i];
        ushort4 o;
        o.x = f2b(v.x); o.y = f2b(v.y); o.z = f2b(v.z); o.w = f2b(v.w);
        ((ushort4*)dst)[i] = o;
    }
}

__global__ void init_stats_kernel(float* stats) {
    if (threadIdx.x < 512) stats[threadIdx.x] = 0.f;
}

// Out[n][o][p] = sum_c W[o][c] * B[n][c][p]  (bf16 in, fp32 acc, bf16 out)
// Tile: 128 o x 128 p, BK=32, 4 waves (each wave: 32 p, all 128 o).
// MODE 0: store bf16 + GN stats atomics (slot 0)
// MODE 1: gated epilogue: sigmoid(v + bgate[o]) * 0.25*(Srow+Scol+2h)
// MODE 2: store bf16 + GN stats atomics (slot 1)
template<int MODE>
__global__ __launch_bounds__(256) void gemm_kernel(
    const u16* __restrict__ Wb,      // [256][256] bf16
    const u16* __restrict__ Bmat,    // [8][256][6400] bf16
    u16* __restrict__ Out,           // [8][256][6400] bf16
    float* __restrict__ stats,
    const u16* __restrict__ Hb,      // MODE1: h (bf16)
    const float* __restrict__ Srow,  // MODE1: [8*256][80]
    const float* __restrict__ Scol,  // MODE1: [8*256][80]
    const float* __restrict__ bgate) // MODE1: [256] fp32
{
    __shared__ __align__(16) u16 sA[128 * 40];   // [o][c], pad 32->40 (2-way free)
    __shared__ __align__(16) u16 sB[128 * 40];   // [p][c]

    const int tid  = threadIdx.x;
    const int lane = tid & 63;
    const int wave = tid >> 6;
    const int m    = lane & 15;
    const int q    = lane >> 4;
    const int p0   = blockIdx.x * 128;
    const int o0   = blockIdx.y * 128;
    const int n    = blockIdx.z;
    const u16* B = Bmat + n * (CC * PP);

    frag_cd acc[8][2];
    #pragma unroll
    for (int i = 0; i < 8; i++)
        #pragma unroll
        for (int j = 0; j < 2; j++)
            #pragma unroll
            for (int k = 0; k < 4; k++) acc[i][j][k] = 0.f;

    const int arow = tid >> 2;          // 0..63
    const int ac   = (tid & 3) * 8;     // 0,8,16,24
    const int bc   = tid & 31;          // 0..31 (c within k-block)
    const int bp   = (tid >> 5) * 16;   // 0..112
    const int wp   = wave * 32;

    for (int kb = 0; kb < CC; kb += 32) {
        frag_ab ar0 = *(const frag_ab*)(Wb + (o0 + arow) * CC + kb + ac);
        frag_ab ar1 = *(const frag_ab*)(Wb + (o0 + 64 + arow) * CC + kb + ac);
        frag_ab br0 = *(const frag_ab*)(B + (kb + bc) * PP + p0 + bp);
        frag_ab br1 = *(const frag_ab*)(B + (kb + bc) * PP + p0 + bp + 8);
        __syncthreads();
        *(frag_ab*)(sA + arow * 40 + ac)        = ar0;
        *(frag_ab*)(sA + (64 + arow) * 40 + ac) = ar1;
        #pragma unroll
        for (int j = 0; j < 8; j++) sB[(bp + j) * 40 + bc]     = (u16)br0[j];
        #pragma unroll
        for (int j = 0; j < 8; j++) sB[(bp + 8 + j) * 40 + bc] = (u16)br1[j];
        __syncthreads();

        frag_ab af[8], bfr[2];
        #pragma unroll
        for (int i = 0; i < 8; i++)
            af[i] = *(const frag_ab*)(sA + (i * 16 + m) * 40 + q * 8);
        #pragma unroll
        for (int j = 0; j < 2; j++)
            bfr[j] = *(const frag_ab*)(sB + (wp + j * 16 + m) * 40 + q * 8);
        #pragma unroll
        for (int i = 0; i < 8; i++)
            #pragma unroll
            for (int j = 0; j < 2; j++)
                acc[i][j] = __builtin_amdgcn_mfma_f32_16x16x32_bf16(af[i], bfr[j], acc[i][j], 0, 0, 0);
    }

    if (MODE == 0 || MODE == 2) {
        float* st = stats + (MODE == 2 ? 256 : 0);
        #pragma unroll
        for (int i = 0; i < 8; i++) {
            float s = 0.f, sq = 0.f;
            #pragma unroll
            for (int j = 0; j < 2; j++) {
                const int p = p0 + wp + j * 16 + m;
                #pragma unroll
                for (int r = 0; r < 4; r++) {
                    const int o = o0 + i * 16 + q * 4 + r;
                    float v = acc[i][j][r];
                    Out[(n * CC + o) * PP + p] = f2b(v);
                    s += v; sq += v * v;
                }
            }
            for (int off = 32; off > 0; off >>= 1) {
                s  += __shfl_down(s, off);
                sq += __shfl_down(sq, off);
            }
            if (lane == 0) {
                const int g = (o0 >> 4) + i;   // 16 channels/group, subtile-aligned
                atomicAdd(&st[n * GG + g], s);
                atomicAdd(&st[128 + n * GG + g], sq);
            }
        }
    } else {
        #pragma unroll
        for (int i = 0; i < 8; i++) {
            #pragma unroll
            for (int j = 0; j < 2; j++) {
                const int p  = p0 + wp + j * 16 + m;
                const int pr = p / WW;
                const int pc = p - pr * WW;
                #pragma unroll
                for (int r = 0; r < 4; r++) {
                    const int o    = o0 + i * 16 + q * 4 + r;
                    const int chan = n * CC + o;
                    float v    = acc[i][j][r] + bgate[o];
                    float gate = sigf(v);
                    float h    = b2f(Hb[chan * PP + p]);
                    // lr+rl+tb+bt = rowsum + colsum + 2h
                    float fused = 0.25f * (Srow[chan * HH + pr] + Scol[chan * WW + pc] + 2.f * h);
                    Out[chan * PP + p] = f2b(fused * gate);
                }
            }
        }
    }
}

// GroupNorm1 + SiLU + row/col sums. One block per (n,c) plane.
__global__ __launch_bounds__(256) void gn1_kernel(
    const u16* __restrict__ c1, u16* __restrict__ hb,
    float* __restrict__ Srow, float* __restrict__ Scol,
    const float* __restrict__ stats,
    const float* __restrict__ g1, const float* __restrict__ b1)
{
    __shared__ float sh[HH * 81];
    const int blk = blockIdx.x;        // n*256 + c
    const int n = blk >> 8, c = blk & 255, g = c >> 4;
    const float s    = stats[n * GG + g];
    const float sq   = stats[128 + n * GG + g];
    const float mean = s * (1.f / GNCNT);
    const float var  = sq * (1.f / GNCNT) - mean * mean;
    const float inv  = rsqrtf(var + 1e-5f);
    const float a    = inv * g1[c];
    const float b    = b1[c] - mean * a;

    const ushort4* src = (const ushort4*)(c1 + blk * PP);
    ushort4*       dst = (ushort4*)(hb + blk * PP);
    for (int e4 = threadIdx.x; e4 < PP / 4; e4 += 256) {
        ushort4 v = src[e4];
        float h0, h1, h2, h3, xn;
        xn = b2f(v.x) * a + b; h0 = xn * sigf(xn);
        xn = b2f(v.y) * a + b; h1 = xn * sigf(xn);
        xn = b2f(v.z) * a + b; h2 = xn * sigf(xn);
        xn = b2f(v.w) * a + b; h3 = xn * sigf(xn);
        ushort4 o; o.x = f2b(h0); o.y = f2b(h1); o.z = f2b(h2); o.w = f2b(h3);
        dst[e4] = o;
        const int e = e4 * 4;
        const int r = e / WW, col = e - r * WW;   // 80%4==0: same row
        float* sp = sh + r * 81 + col;
        sp[0] = h0; sp[1] = h1; sp[2] = h2; sp[3] = h3;
    }
    __syncthreads();
    const int tid = threadIdx.x;
    if (tid < HH) {
        float r = 0.f;
        for (int j = 0; j < WW; j++) r += sh[tid * 81 + j];
        Srow[blk * HH + tid] = r;
    } else if (tid < 2 * HH) {
        const int j = tid - HH;
        float r = 0.f;
        for (int i = 0; i < HH; i++) r += sh[i * 81 + j];
        Scol[blk * WW + j] = r;
    }
}

// depthwise 3x3 zero-pad, bf16 -> bf16. One block per (n,c) plane.
__global__ __launch_bounds__(256) void dw_kernel(
    const u16* __restrict__ gin, u16* __restrict__ dout,
    const float* __restrict__ wdw)
{
    __shared__ float sh[HH * 81];
    const int blk = blockIdx.x;
    const int c   = blk & 255;
    float wreg[9];
    #pragma unroll
    for (int k = 0; k < 9; k++) wreg[k] = wdw[c * 9 + k];

    const ushort4* src = (const ushort4*)(gin + blk * PP);
    for (int e4 = threadIdx.x; e4 < PP / 4; e4 += 256) {
        ushort4 v = src[e4];
        const int e = e4 * 4;
        const int r = e / WW, col = e - r * WW;
        float* sp = sh + r * 81 + col;
        sp[0] = b2f(v.x); sp[1] = b2f(v.y); sp[2] = b2f(v.z); sp[3] = b2f(v.w);
    }
    __syncthreads();
    ushort4* dst = (ushort4*)(dout + blk * PP);
    for (int e4 = threadIdx.x; e4 < PP / 4; e4 += 256) {
        const int e = e4 * 4;
        const int i = e / WW, j0 = e - (e / WW) * WW;
        ushort4 o;
        u16* op = (u16*)&o;
        #pragma unroll
        for (int t = 0; t < 4; t++) {
            const int j = j0 + t;
            float acc = 0.f;
            #pragma unroll
            for (int di = -1; di <= 1; di++) {
                const int ii = i + di;
                if (ii < 0 || ii >= HH) continue;
                #pragma unroll
                for (int dj = -1; dj <= 1; dj++) {
                    const int jj = j + dj;
                    if (jj < 0 || jj >= WW) continue;
                    acc += wreg[(di + 1) * 3 + (dj + 1)] * sh[ii * 81 + jj];
                }
            }
            op[t] = f2b(acc);
        }
        dst[e4] = o;
    }
}

// GroupNorm2 + SiLU -> fp32 output
__global__ __launch_bounds__(256) void gn2_kernel(
    const u16* __restrict__ y, float* __restrict__ out,
    const float* __restrict__ stats,
    const float* __restrict__ g2, const float* __restrict__ b2v)
{
    const int blk = blockIdx.x;
    const int n = blk >> 8, c = blk & 255, g = c >> 4;
    const float s    = stats[256 + n * GG + g];
    const float sq   = stats[384 + n * GG + g];
    const float mean = s * (1.f / GNCNT);
    const float var  = sq * (1.f / GNCNT) - mean * mean;
    const float inv  = rsqrtf(var + 1e-5f);
    const float a    = inv * g2[c];
    const float b    = b2v[c] - mean * a;
    const ushort4* src = (const ushort4*)(y + blk * PP);
    float4*        dst = (float4*)(out + blk * PP);
    for (int e4 = threadIdx.x; e4 < PP / 4; e4 += 256) {
        ushort4 v = src[e4];
        float4 o; float xn;
        xn = b2f(v.x) * a + b; o.x = xn * sigf(xn);
        xn = b2f(v.y) * a + b; o.y = xn * sigf(xn);
        xn = b2f(v.z) * a + b; o.z = xn * sigf(xn);
        xn = b2f(v.w) * a + b; o.w = xn * sigf(xn);
        dst[e4] = o;
    }
}

extern "C" void kernel_launch(void* const* d_in, const int* in_sizes, int n_in,
                              void* d_out, int out_size, void* d_ws, size_t ws_size,
                              hipStream_t stream)
{
    const float* x      = (const float*)d_in[0];
    const float* w_pre  = (const float*)d_in[1];
    const float* g1     = (const float*)d_in[2];
    const float* b1     = (const float*)d_in[3];
    const float* w_gate = (const float*)d_in[4];
    const float* b_gate = (const float*)d_in[5];
    const float* w_dw   = (const float*)d_in[6];
    const float* w_pw   = (const float*)d_in[7];
    const float* g2     = (const float*)d_in[8];
    const float* b2     = (const float*)d_in[9];
    float* out = (float*)d_out;

    char* ws = (char*)d_ws;
    u16*   wb    = (u16*)(ws);                      // 3 x 65536 bf16 = 393,216 B
    u16*   xb    = (u16*)(ws + 524288);             // 26,214,400 B
    u16*   bufA  = (u16*)(ws + 26738688);           // 26,214,400 B
    u16*   bufB  = (u16*)(ws + 52953088);           // 26,214,400 B
    float* Srow  = (float*)(ws + 79167488);         // 655,360 B
    float* Scol  = (float*)(ws + 79822848);         // 655,360 B
    float* stats = (float*)(ws + 80478208);         // 2,048 B

    u16* wb0 = wb;            // w_pre
    u16* wb1 = wb + 65536;    // w_gate
    u16* wb2 = wb + 131072;   // w_pw

    // prep: fp32 -> bf16
    cvt_kernel<<<12800, 256, 0, stream>>>(x, xb, 3276800);
    cvt_kernel<<<64, 256, 0, stream>>>(w_pre,  wb0, 16384);
    cvt_kernel<<<64, 256, 0, stream>>>(w_gate, wb1, 16384);
    cvt_kernel<<<64, 256, 0, stream>>>(w_pw,   wb2, 16384);
    init_stats_kernel<<<1, 512, 0, stream>>>(stats);

    dim3 ggrid(50, 2, 8);   // p-tiles(128) x o-tiles(128) x n
    // conv1 + GN1 stats
    gemm_kernel<0><<<ggrid, 256, 0, stream>>>(wb0, xb, bufA, stats,
                                              nullptr, nullptr, nullptr, nullptr);
    // GN1 + SiLU + row/col sums
    gn1_kernel<<<2048, 256, 0, stream>>>(bufA, bufB, Srow, Scol, stats, g1, b1);
    // gate conv + fused-scan gating
    gemm_kernel<1><<<ggrid, 256, 0, stream>>>(wb1, bufB, bufA, stats,
                                              bufB, Srow, Scol, b_gate);
    // depthwise 3x3
    dw_kernel<<<2048, 256, 0, stream>>>(bufA, bufB, w_dw);
    // conv3 + GN2 stats
    gemm_kernel<2><<<ggrid, 256, 0, stream>>>(wb2, bufB, bufA, stats,
                                              nullptr, nullptr, nullptr, nullptr);
    // GN2 + SiLU -> fp32 out
    gn2_kernel<<<2048, 256, 0, stream>>>(bufA, out, stats, g2, b2);
}

// Round 3
// 438.198 us; speedup vs baseline: 1.0126x; 1.0126x over previous
//
#include <hip/hip_runtime.h>
#include <stdint.h>

#define CC 256
#define HH 80
#define WW 80
#define PP 6400          // 80*80
#define GG 16
#define GNCNT (16*6400)  // per (n,group): 16 channels * 6400 pixels

using frag_ab = __attribute__((ext_vector_type(8))) short;   // 8 bf16
using frag_cd = __attribute__((ext_vector_type(4))) float;   // 4 fp32
typedef unsigned short u16;

__device__ __forceinline__ float b2f(u16 u) {
    union { float f; uint32_t i; } v; v.i = ((uint32_t)u) << 16; return v.f;
}
__device__ __forceinline__ u16 f2b(float f) {
    uint32_t x = __float_as_uint(f);
    return (u16)((x + 0x7fffu + ((x >> 16) & 1u)) >> 16);  // RNE
}
__device__ __forceinline__ float sigf(float x) { return 1.f / (1.f + __expf(-x)); }

// plain fp32 -> bf16 (weights)
__global__ __launch_bounds__(256) void cvt_kernel(const float* __restrict__ src,
                                                  u16* __restrict__ dst, int n4) {
    int i = blockIdx.x * 256 + threadIdx.x;
    if (i < n4) {
        float4 v = ((const float4*)src)[i];
        ushort4 o;
        o.x = f2b(v.x); o.y = f2b(v.y); o.z = f2b(v.z); o.w = f2b(v.w);
        ((ushort4*)dst)[i] = o;
    }
}

// x [n][c][p] fp32 -> Xt [n][p][c] bf16.  64c x 64p tile per block.
__global__ __launch_bounds__(256) void cvtT_kernel(const float* __restrict__ x,
                                                   u16* __restrict__ Xt) {
    __shared__ u16 sT[64 * 72];   // [p][c], pad 64->72
    const int p0 = blockIdx.x * 64, c0 = blockIdx.y * 64, n = blockIdx.z;
    const int t = threadIdx.x;
    {   // phase 1: read x rows (coalesced along p), scatter bf16 into sT[p][c]
        const int cl = t >> 2, pq = t & 3;
        const float* row = x + ((size_t)(n * CC + c0 + cl)) * PP + p0 + pq * 16;
        #pragma unroll
        for (int u = 0; u < 4; u++) {
            float4 v = ((const float4*)(row + u * 4))[0];
            const int pp = pq * 16 + u * 4;
            sT[(pp + 0) * 72 + cl] = f2b(v.x);
            sT[(pp + 1) * 72 + cl] = f2b(v.y);
            sT[(pp + 2) * 72 + cl] = f2b(v.z);
            sT[(pp + 3) * 72 + cl] = f2b(v.w);
        }
    }
    __syncthreads();
    {   // phase 2: write Xt rows (coalesced along c)
        const int pl = t >> 2, cq = t & 3;
        u16* orow = Xt + ((size_t)(n * PP + p0 + pl)) * CC + c0 + cq * 16;
        *(frag_ab*)(orow)     = *(const frag_ab*)(sT + pl * 72 + cq * 16);
        *(frag_ab*)(orow + 8) = *(const frag_ab*)(sT + pl * 72 + cq * 16 + 8);
    }
}

// Out[m][o] = sum_c A[m][c] * W[o][c]; m = n*6400+p.  Tile 128m x 64o, barrier-free K-loop.
// A-fragments direct from global; W staged once in LDS in fragment order.
// MODE 0/2: store bf16 + GN stats atomics (slot 0 / 1).  MODE 1: gate epilogue.
template<int MODE>
__global__ __launch_bounds__(256, 4) void gemm_kernel(
    const u16* __restrict__ A,       // [51200][256] bf16
    const u16* __restrict__ Wb,      // [256][256] bf16
    u16* __restrict__ Out,           // [51200][256] bf16
    float* __restrict__ stats,
    const u16* __restrict__ Hb,      // MODE1: h, same layout as A
    const float* __restrict__ Srow,  // MODE1: [8*80][256]
    const float* __restrict__ Scol,  // MODE1: [8*80][256]
    const float* __restrict__ bgate) // MODE1: [256]
{
    // fragment-order W: off(kc,j,q,m,jj) = ((kc*4+j)*64 + q*16 + m)*8 + jj
    __shared__ __align__(16) u16 sW[8 * 4 * 512];   // 32 KB

    const int t    = threadIdx.x;
    const int lane = t & 63;
    const int wave = t >> 6;
    const int m    = lane & 15;
    const int q    = lane >> 4;
    const int o0   = blockIdx.y * 64;
    const int mrow = blockIdx.x * 128 + wave * 32;   // this wave's first m row
    const int n    = (blockIdx.x * 128) / PP;        // 6400 % 128 == 0: uniform

    // stage W[o0..o0+63][0..255] into fragment order (once)
    {
        const int ol = t >> 2;            // 0..63
        const int cq = (t & 3) * 64;      // 0,64,128,192
        const u16* wrow = Wb + (o0 + ol) * CC + cq;
        const int j = ol >> 4, mm = ol & 15;
        #pragma unroll
        for (int u = 0; u < 8; u++) {
            const int c  = cq + u * 8;
            const int kc = c >> 5, qq = (c >> 3) & 3;
            *(frag_ab*)(sW + ((kc * 4 + j) * 64 + qq * 16 + mm) * 8) =
                *(const frag_ab*)(wrow + u * 8);
        }
    }
    __syncthreads();

    frag_cd acc[2][4];
    #pragma unroll
    for (int i = 0; i < 2; i++)
        #pragma unroll
        for (int j = 0; j < 4; j++)
            #pragma unroll
            for (int k = 0; k < 4; k++) acc[i][j][k] = 0.f;

    const u16* arow = A + (size_t)(mrow + m) * CC + q * 8;   // lane's A row base

    #pragma unroll
    for (int kc = 0; kc < 8; kc++) {
        frag_ab af0 = *(const frag_ab*)(arow + kc * 32);
        frag_ab af1 = *(const frag_ab*)(arow + 16 * CC + kc * 32);
        const u16* wp = sW + kc * 2048 + lane * 8;
        #pragma unroll
        for (int j = 0; j < 4; j++) {
            frag_ab bf = *(const frag_ab*)(wp + j * 512);
            acc[0][j] = __builtin_amdgcn_mfma_f32_16x16x32_bf16(af0, bf, acc[0][j], 0, 0, 0);
            acc[1][j] = __builtin_amdgcn_mfma_f32_16x16x32_bf16(af1, bf, acc[1][j], 0, 0, 0);
        }
    }

    if (MODE == 0 || MODE == 2) {
        float* st = stats + (MODE == 2 ? 256 : 0);
        #pragma unroll
        for (int j = 0; j < 4; j++) {
            float s = 0.f, sq = 0.f;
            #pragma unroll
            for (int i = 0; i < 2; i++) {
                #pragma unroll
                for (int r = 0; r < 4; r++) {
                    const int row = mrow + i * 16 + q * 4 + r;
                    float v = acc[i][j][r];
                    Out[(size_t)row * CC + o0 + j * 16 + m] = f2b(v);
                    s += v; sq += v * v;
                }
            }
            #pragma unroll
            for (int off = 32; off > 0; off >>= 1) {
                s  += __shfl_down(s, off);
                sq += __shfl_down(sq, off);
            }
            if (lane == 0) {
                const int g = (o0 >> 4) + j;
                atomicAdd(&st[n * GG + g], s);
                atomicAdd(&st[128 + n * GG + g], sq);
            }
        }
    } else {
        #pragma unroll
        for (int i = 0; i < 2; i++) {
            #pragma unroll
            for (int r = 0; r < 4; r++) {
                const int row = mrow + i * 16 + q * 4 + r;
                const int pl  = row - n * PP;
                const int pr  = pl / WW;
                const int pc  = pl - pr * WW;
                const float* srp = Srow + (size_t)(n * HH + pr) * CC + o0 + m;
                const float* scp = Scol + (size_t)(n * HH + pc) * CC + o0 + m;
                #pragma unroll
                for (int j = 0; j < 4; j++) {
                    const int oc = o0 + j * 16 + m;
                    float v    = acc[i][j][r] + bgate[oc];
                    float gate = sigf(v);
                    float h    = b2f(Hb[(size_t)row * CC + oc]);
                    float fused = 0.25f * (srp[j * 16] + scp[j * 16] + 2.f * h);
                    Out[(size_t)row * CC + oc] = f2b(fused * gate);
                }
            }
        }
    }
}

// GN1 + SiLU + Srow.  Block per (i-row, n): 80 j x 256 c.
__global__ __launch_bounds__(256) void gn1_kernel(
    const u16* __restrict__ c1, u16* __restrict__ hb,
    float* __restrict__ Srow,
    const float* __restrict__ stats,
    const float* __restrict__ g1, const float* __restrict__ b1)
{
    __shared__ float sred[8 * 256];
    const int i = blockIdx.x, n = blockIdx.y;
    const int t = threadIdx.x;
    const int jg = t >> 5, cc = t & 31;
    const int c8 = cc * 8;
    const int g  = cc >> 1;   // 8c chunk within one 16c group
    const float su   = stats[n * GG + g];
    const float sq   = stats[128 + n * GG + g];
    const float mean = su * (1.f / GNCNT);
    const float var  = sq * (1.f / GNCNT) - mean * mean;
    const float inv  = rsqrtf(var + 1e-5f);
    float a[8], b[8];
    #pragma unroll
    for (int k = 0; k < 8; k++) {
        a[k] = inv * g1[c8 + k];
        b[k] = b1[c8 + k] - mean * a[k];
    }
    float srow8[8];
    #pragma unroll
    for (int k = 0; k < 8; k++) srow8[k] = 0.f;

    const size_t base = (size_t)(n * PP + i * WW) * CC;
    for (int s = 0; s < 10; s++) {
        const int j = jg + s * 8;
        const u16* src = c1 + base + (size_t)j * CC + c8;
        u16*       dst = hb + base + (size_t)j * CC + c8;
        frag_ab v = *(const frag_ab*)src;
        frag_ab o;
        #pragma unroll
        for (int k = 0; k < 8; k++) {
            float xn = b2f((u16)v[k]) * a[k] + b[k];
            float hs = xn * sigf(xn);
            o[k] = (short)f2b(hs);
            srow8[k] += hs;
        }
        *(frag_ab*)dst = o;
    }
    #pragma unroll
    for (int k = 0; k < 8; k++) sred[jg * 256 + c8 + k] = srow8[k];
    __syncthreads();
    {
        const int c = t;
        float s = 0.f;
        #pragma unroll
        for (int k = 0; k < 8; k++) s += sred[k * 256 + c];
        Srow[(size_t)(n * HH + i) * CC + c] = s;
    }
}

// Scol[n][j][c] = sum_i hs[n][i*80+j][c].  Block (jg, iq, n); atomics (Scol pre-zeroed).
__global__ __launch_bounds__(256) void scol_kernel(
    const u16* __restrict__ hb, float* __restrict__ Scol)
{
    const int jg = blockIdx.x, iq = blockIdx.y, n = blockIdx.z;
    const int t = threadIdx.x;
    const int js = t >> 5, cc = t & 31;
    const int j = jg * 8 + js, c8 = cc * 8;
    float acc8[8];
    #pragma unroll
    for (int k = 0; k < 8; k++) acc8[k] = 0.f;
    for (int s = 0; s < 20; s++) {
        const int i = iq * 20 + s;
        frag_ab v = *(const frag_ab*)(hb + (size_t)(n * PP + i * WW + j) * CC + c8);
        #pragma unroll
        for (int k = 0; k < 8; k++) acc8[k] += b2f((u16)v[k]);
    }
    float* dst = Scol + (size_t)(n * HH + j) * CC + c8;
    #pragma unroll
    for (int k = 0; k < 8; k++) atomicAdd(&dst[k], acc8[k]);
}

// depthwise 3x3 zero-pad in [p][c] layout.  Block (i, chalf, n).
__global__ __launch_bounds__(256) void dw_kernel(
    const u16* __restrict__ gin, u16* __restrict__ dout,
    const float* __restrict__ wdw)
{
    __shared__ float sw[1152];   // 128 c * 9
    const int i = blockIdx.x, chalf = blockIdx.y, n = blockIdx.z;
    const int t = threadIdx.x;
    for (int u = t; u < 1152; u += 256) sw[u] = wdw[chalf * 1152 + u];
    __syncthreads();

    const int jg = t >> 5, cc = t & 31;
    const int gc = chalf * 128 + cc * 4;   // global c of 4-chunk
    float wl[4][9];
    #pragma unroll
    for (int cl = 0; cl < 4; cl++)
        #pragma unroll
        for (int k = 0; k < 9; k++) wl[cl][k] = sw[(cc * 4 + cl) * 9 + k];

    const size_t nbase = (size_t)n * PP * CC;
    for (int s = 0; s < 10; s++) {
        const int j = jg + s * 8;
        float acc4[4] = {0.f, 0.f, 0.f, 0.f};
        #pragma unroll
        for (int di = -1; di <= 1; di++) {
            const int ii = i + di;
            if (ii < 0 || ii >= HH) continue;
            #pragma unroll
            for (int dj = -1; dj <= 1; dj++) {
                const int jj = j + dj;
                if (jj < 0 || jj >= WW) continue;
                ushort4 v = *(const ushort4*)(gin + nbase + (size_t)(ii * WW + jj) * CC + gc);
                const int k = (di + 1) * 3 + (dj + 1);
                acc4[0] += wl[0][k] * b2f(v.x);
                acc4[1] += wl[1][k] * b2f(v.y);
                acc4[2] += wl[2][k] * b2f(v.z);
                acc4[3] += wl[3][k] * b2f(v.w);
            }
        }
        ushort4 o;
        o.x = f2b(acc4[0]); o.y = f2b(acc4[1]); o.z = f2b(acc4[2]); o.w = f2b(acc4[3]);
        *(ushort4*)(dout + nbase + (size_t)(i * WW + j) * CC + gc) = o;
    }
}

// GN2 + SiLU + transpose-out: Y [n][p][c] bf16 -> out [n][c][p] fp32.  64p x 64c tile.
__global__ __launch_bounds__(256) void gn2T_kernel(
    const u16* __restrict__ Y, float* __restrict__ out,
    const float* __restrict__ stats,
    const float* __restrict__ g2, const float* __restrict__ b2v)
{
    __shared__ u16 sT[64 * 72];
    const int p0 = blockIdx.x * 64, c0 = blockIdx.y * 64, n = blockIdx.z;
    const int t = threadIdx.x;
    {   // phase 1: read Y rows (coalesced along c)
        const int pl = t >> 2, cq = t & 3;
        const u16* row = Y + (size_t)(n * PP + p0 + pl) * CC + c0 + cq * 16;
        *(frag_ab*)(sT + pl * 72 + cq * 16)     = *(const frag_ab*)(row);
        *(frag_ab*)(sT + pl * 72 + cq * 16 + 8) = *(const frag_ab*)(row + 8);
    }
    __syncthreads();
    {   // phase 2: per-c affine + silu, write out rows (coalesced along p)
        const int cl = t >> 2, pq = t & 3;
        const int c = c0 + cl, g = c >> 4;
        const float su   = stats[256 + n * GG + g];
        const float sq   = stats[384 + n * GG + g];
        const float mean = su * (1.f / GNCNT);
        const float var  = sq * (1.f / GNCNT) - mean * mean;
        const float inv  = rsqrtf(var + 1e-5f);
        const float a    = inv * g2[c];
        const float b    = b2v[c] - mean * a;
        float* orow = out + (size_t)(n * CC + c) * PP + p0 + pq * 16;
        #pragma unroll
        for (int u4 = 0; u4 < 4; u4++) {
            float4 o;
            float* op = (float*)&o;
            #pragma unroll
            for (int e = 0; e < 4; e++) {
                const int pp = pq * 16 + u4 * 4 + e;
                float xn = b2f(sT[pp * 72 + cl]) * a + b;
                op[e] = xn * sigf(xn);
            }
            ((float4*)(orow + u4 * 4))[0] = o;
        }
    }
}

extern "C" void kernel_launch(void* const* d_in, const int* in_sizes, int n_in,
                              void* d_out, int out_size, void* d_ws, size_t ws_size,
                              hipStream_t stream)
{
    const float* x      = (const float*)d_in[0];
    const float* w_pre  = (const float*)d_in[1];
    const float* g1     = (const float*)d_in[2];
    const float* b1     = (const float*)d_in[3];
    const float* w_gate = (const float*)d_in[4];
    const float* b_gate = (const float*)d_in[5];
    const float* w_dw   = (const float*)d_in[6];
    const float* w_pw   = (const float*)d_in[7];
    const float* g2     = (const float*)d_in[8];
    const float* b2     = (const float*)d_in[9];
    float* out = (float*)d_out;

    char* ws = (char*)d_ws;
    u16*   wb0   = (u16*)(ws);                      // 131,072 B
    u16*   wb1   = (u16*)(ws + 131072);             // 131,072 B
    u16*   wb2   = (u16*)(ws + 262144);             // 131,072 B
    u16*   Xt    = (u16*)(ws + 393216);             // 26,214,400 B
    u16*   bufA  = (u16*)(ws + 26607616);           // 26,214,400 B
    u16*   bufB  = (u16*)(ws + 52822016);           // 26,214,400 B
    float* Srow  = (float*)(ws + 79036416);         // 655,360 B
    float* Scol  = (float*)(ws + 79691776);         // 655,360 B
    float* stats = (float*)(ws + 80347136);         // 2,048 B

    hipMemsetAsync(stats, 0, 2048, stream);
    hipMemsetAsync(Scol, 0, 655360, stream);

    cvt_kernel<<<64, 256, 0, stream>>>(w_pre,  wb0, 16384);
    cvt_kernel<<<64, 256, 0, stream>>>(w_gate, wb1, 16384);
    cvt_kernel<<<64, 256, 0, stream>>>(w_pw,   wb2, 16384);
    cvtT_kernel<<<dim3(100, 4, 8), 256, 0, stream>>>(x, Xt);

    dim3 ggrid(400, 4);   // m-tiles(128) x o-tiles(64)
    // conv1 + GN1 stats
    gemm_kernel<0><<<ggrid, 256, 0, stream>>>(Xt, wb0, bufA, stats,
                                              nullptr, nullptr, nullptr, nullptr);
    // GN1 + SiLU + Srow
    gn1_kernel<<<dim3(80, 8), 256, 0, stream>>>(bufA, bufB, Srow, stats, g1, b1);
    // Scol
    scol_kernel<<<dim3(10, 4, 8), 256, 0, stream>>>(bufB, Scol);
    // gate conv + fused-scan gating
    gemm_kernel<1><<<ggrid, 256, 0, stream>>>(bufB, wb1, bufA, stats,
                                              bufB, Srow, Scol, b_gate);
    // depthwise 3x3
    dw_kernel<<<dim3(80, 2, 8), 256, 0, stream>>>(bufA, bufB, w_dw);
    // conv3 + GN2 stats
    gemm_kernel<2><<<ggrid, 256, 0, stream>>>(bufB, wb2, bufA, stats,
                                              nullptr, nullptr, nullptr, nullptr);
    // GN2 + SiLU -> fp32 out (transposed)
    gn2T_kernel<<<dim3(100, 4, 8), 256, 0, stream>>>(bufA, out, stats, g2, b2);
}

// Round 4
// 436.723 us; speedup vs baseline: 1.0161x; 1.0034x over previous
//
#include <hip/hip_runtime.h>
#include <stdint.h>

#define CC 256
#define HH 80
#define WW 80
#define PP 6400          // 80*80
#define GG 16
#define GNCNT (16*6400)  // per (n,group): 16 channels * 6400 pixels

using frag_ab = __attribute__((ext_vector_type(8))) short;   // 8 bf16 (4 VGPRs)
using frag_cd = __attribute__((ext_vector_type(4))) float;   // 4 fp32
typedef unsigned short u16;

__device__ __forceinline__ float b2f(u16 u) {
    union { float f; uint32_t i; } v; v.i = ((uint32_t)u) << 16; return v.f;
}
__device__ __forceinline__ u16 f2b(float f) {
    uint32_t x = __float_as_uint(f);
    return (u16)((x + 0x7fffu + ((x >> 16) & 1u)) >> 16);  // RNE
}
__device__ __forceinline__ float sigf(float x) { return 1.f / (1.f + __expf(-x)); }

// plain fp32 -> bf16 (weights)
__global__ __launch_bounds__(256) void cvt_kernel(const float* __restrict__ src,
                                                  u16* __restrict__ dst, int n4) {
    int i = blockIdx.x * 256 + threadIdx.x;
    if (i < n4) {
        float4 v = ((const float4*)src)[i];
        ushort4 o;
        o.x = f2b(v.x); o.y = f2b(v.y); o.z = f2b(v.z); o.w = f2b(v.w);
        ((ushort4*)dst)[i] = o;
    }
}

// x [n][c][p] fp32 -> Xt [n][p][c] bf16.  64c x 64p tile per block.
__global__ __launch_bounds__(256) void cvtT_kernel(const float* __restrict__ x,
                                                   u16* __restrict__ Xt) {
    __shared__ u16 sT[64 * 72];   // [p][c], pad 64->72
    const int p0 = blockIdx.x * 64, c0 = blockIdx.y * 64, n = blockIdx.z;
    const int t = threadIdx.x;
    {   // phase 1: read x rows (coalesced along p), scatter bf16 into sT[p][c]
        const int cl = t >> 2, pq = t & 3;
        const float* row = x + ((size_t)(n * CC + c0 + cl)) * PP + p0 + pq * 16;
        #pragma unroll
        for (int u = 0; u < 4; u++) {
            float4 v = ((const float4*)(row + u * 4))[0];
            const int pp = pq * 16 + u * 4;
            sT[(pp + 0) * 72 + cl] = f2b(v.x);
            sT[(pp + 1) * 72 + cl] = f2b(v.y);
            sT[(pp + 2) * 72 + cl] = f2b(v.z);
            sT[(pp + 3) * 72 + cl] = f2b(v.w);
        }
    }
    __syncthreads();
    {   // phase 2: write Xt rows (coalesced along c)
        const int pl = t >> 2, cq = t & 3;
        u16* orow = Xt + ((size_t)(n * PP + p0 + pl)) * CC + c0 + cq * 16;
        *(frag_ab*)(orow)     = *(const frag_ab*)(sT + pl * 72 + cq * 16);
        *(frag_ab*)(orow + 8) = *(const frag_ab*)(sT + pl * 72 + cq * 16 + 8);
    }
}

// Out[m][o] = sum_c A[m][c] * W[o][c]; m = n*6400+p.  Tile 128m x 64o.
// W staged once in LDS (fragment order); A prefetched to 16 reg fragments AFTER
// the staging barrier (so the barrier's vmcnt(0) drain can't serialize them);
// barrier-free MFMA K-loop; epilogue repacked through LDS for full-line stores.
// MODE 0/2: store bf16 + GN stats atomics (slot 0 / 1).  MODE 1: gate epilogue.
template<int MODE>
__global__ __launch_bounds__(256, 3) void gemm_kernel(
    const u16* __restrict__ A,       // [51200][256] bf16
    const u16* __restrict__ Wb,      // [256][256] bf16
    u16* __restrict__ Out,           // [51200][256] bf16
    float* __restrict__ stats,
    const u16* __restrict__ Hb,      // MODE1: h, same layout as A
    const float* __restrict__ Srow,  // MODE1: [8*80][256]
    const float* __restrict__ Scol,  // MODE1: [8*80][256]
    const float* __restrict__ bgate) // MODE1: [256]
{
    // 36 KB: first used as fragment-order W (32 KB), then reused for C repack.
    __shared__ __align__(16) u16 smem[18432];
    u16* sW = smem;

    const int t    = threadIdx.x;
    const int lane = t & 63;
    const int wave = t >> 6;
    const int m    = lane & 15;
    const int q    = lane >> 4;
    const int o0   = blockIdx.y * 64;
    const int mrow = blockIdx.x * 128 + wave * 32;   // this wave's first m row
    const int n    = blockIdx.x / 50;                // 128*50 = 6400 rows per n

    // ---- stage W[o0..o0+63][0..255] into fragment order (once) ----
    // off(kc,j,q,m,jj) = ((kc*4+j)*64 + q*16 + m)*8 + jj
    {
        const int ol = t >> 2;            // 0..63
        const int cq = (t & 3) * 64;      // 0,64,128,192
        const u16* wrow = Wb + (o0 + ol) * CC + cq;
        const int j = ol >> 4, mm = ol & 15;
        #pragma unroll
        for (int u = 0; u < 8; u++) {
            const int c  = cq + u * 8;
            const int kc = c >> 5, qq = (c >> 3) & 3;
            *(frag_ab*)(sW + ((kc * 4 + j) * 64 + qq * 16 + mm) * 8) =
                *(const frag_ab*)(wrow + u * 8);
        }
    }
    __syncthreads();

    // ---- A prefetch: 16 independent loads, all in flight ----
    const u16* arow = A + (size_t)(mrow + m) * CC + q * 8;
    frag_ab a0[8], a1[8];
    #pragma unroll
    for (int kc = 0; kc < 8; kc++) {
        a0[kc] = *(const frag_ab*)(arow + kc * 32);
        a1[kc] = *(const frag_ab*)(arow + 16 * CC + kc * 32);
    }

    frag_cd acc[2][4];
    #pragma unroll
    for (int i = 0; i < 2; i++)
        #pragma unroll
        for (int j = 0; j < 4; j++)
            #pragma unroll
            for (int k = 0; k < 4; k++) acc[i][j][k] = 0.f;

    #pragma unroll
    for (int kc = 0; kc < 8; kc++) {
        const u16* wp = sW + kc * 2048 + lane * 8;
        #pragma unroll
        for (int j = 0; j < 4; j++) {
            frag_ab bf = *(const frag_ab*)(wp + j * 512);
            acc[0][j] = __builtin_amdgcn_mfma_f32_16x16x32_bf16(a0[kc], bf, acc[0][j], 0, 0, 0);
            acc[1][j] = __builtin_amdgcn_mfma_f32_16x16x32_bf16(a1[kc], bf, acc[1][j], 0, 0, 0);
        }
    }
    __syncthreads();   // all waves done reading sW; safe to reuse for repack

    if (MODE == 0 || MODE == 2) {
        // GN stats
        float* st = stats + (MODE == 2 ? 256 : 0);
        #pragma unroll
        for (int j = 0; j < 4; j++) {
            float s = 0.f, sq = 0.f;
            #pragma unroll
            for (int i = 0; i < 2; i++)
                #pragma unroll
                for (int r = 0; r < 4; r++) {
                    float v = acc[i][j][r];
                    s += v; sq += v * v;
                }
            #pragma unroll
            for (int off = 32; off > 0; off >>= 1) {
                s  += __shfl_down(s, off);
                sq += __shfl_down(sq, off);
            }
            if (lane == 0) {
                const int g = (o0 >> 4) + j;
                atomicAdd(&st[n * GG + g], s);
                atomicAdd(&st[128 + n * GG + g], sq);
            }
        }
        // repack: per-wave 32 rows x 72 cols (u16), then full-line stores
        u16* myT = smem + wave * (32 * 72);
        #pragma unroll
        for (int i = 0; i < 2; i++)
            #pragma unroll
            for (int j = 0; j < 4; j++)
                #pragma unroll
                for (int r = 0; r < 4; r++)
                    myT[(i * 16 + q * 4 + r) * 72 + j * 16 + m] = f2b(acc[i][j][r]);
        #pragma unroll
        for (int u = 0; u < 4; u++) {
            const int rr = u * 8 + (lane >> 3);
            frag_ab v = *(const frag_ab*)(myT + rr * 72 + (lane & 7) * 8);
            *(frag_ab*)(Out + (size_t)(mrow + rr) * CC + o0 + (lane & 7) * 8) = v;
        }
    } else {
        // gates (fp32) through LDS: per-wave 32 rows x 72 cols (f32)
        float* myG = (float*)smem + wave * (32 * 72);
        float bg[4];
        #pragma unroll
        for (int j = 0; j < 4; j++) bg[j] = bgate[o0 + j * 16 + m];
        #pragma unroll
        for (int i = 0; i < 2; i++)
            #pragma unroll
            for (int j = 0; j < 4; j++)
                #pragma unroll
                for (int r = 0; r < 4; r++)
                    myG[(i * 16 + q * 4 + r) * 72 + j * 16 + m] = sigf(acc[i][j][r] + bg[j]);
        #pragma unroll
        for (int u = 0; u < 8; u++) {
            const int rr = u * 4 + (lane >> 4);       // row within wave tile
            const int col = (lane & 15) * 4;          // o offset (4 floats)
            float4 g4 = *(const float4*)(myG + rr * 72 + col);
            const int row = mrow + rr;
            const int pl  = row - n * PP;
            const int pr  = pl / WW;
            const int pc  = pl - pr * WW;
            const int o   = o0 + col;
            ushort4 hv = *(const ushort4*)(Hb + (size_t)row * CC + o);
            float4  sr = *(const float4*)(Srow + (size_t)(n * HH + pr) * CC + o);
            float4  sc = *(const float4*)(Scol + (size_t)(n * HH + pc) * CC + o);
            ushort4 ov;
            ov.x = f2b(0.25f * (sr.x + sc.x + 2.f * b2f(hv.x)) * g4.x);
            ov.y = f2b(0.25f * (sr.y + sc.y + 2.f * b2f(hv.y)) * g4.y);
            ov.z = f2b(0.25f * (sr.z + sc.z + 2.f * b2f(hv.z)) * g4.z);
            ov.w = f2b(0.25f * (sr.w + sc.w + 2.f * b2f(hv.w)) * g4.w);
            *(ushort4*)(Out + (size_t)row * CC + o) = ov;
        }
    }
}

// GN1 + SiLU + Srow.  Block per (i-row, n): 80 j x 256 c.
__global__ __launch_bounds__(256) void gn1_kernel(
    const u16* __restrict__ c1, u16* __restrict__ hb,
    float* __restrict__ Srow,
    const float* __restrict__ stats,
    const float* __restrict__ g1, const float* __restrict__ b1)
{
    __shared__ float sred[8 * 256];
    const int i = blockIdx.x, n = blockIdx.y;
    const int t = threadIdx.x;
    const int jg = t >> 5, cc = t & 31;
    const int c8 = cc * 8;
    const int g  = cc >> 1;   // 8c chunk within one 16c group
    const float su   = stats[n * GG + g];
    const float sq   = stats[128 + n * GG + g];
    const float mean = su * (1.f / GNCNT);
    const float var  = sq * (1.f / GNCNT) - mean * mean;
    const float inv  = rsqrtf(var + 1e-5f);
    float a[8], b[8];
    #pragma unroll
    for (int k = 0; k < 8; k++) {
        a[k] = inv * g1[c8 + k];
        b[k] = b1[c8 + k] - mean * a[k];
    }
    float srow8[8];
    #pragma unroll
    for (int k = 0; k < 8; k++) srow8[k] = 0.f;

    const size_t base = (size_t)(n * PP + i * WW) * CC;
    for (int s = 0; s < 10; s++) {
        const int j = jg + s * 8;
        const u16* src = c1 + base + (size_t)j * CC + c8;
        u16*       dst = hb + base + (size_t)j * CC + c8;
        frag_ab v = *(const frag_ab*)src;
        frag_ab o;
        #pragma unroll
        for (int k = 0; k < 8; k++) {
            float xn = b2f((u16)v[k]) * a[k] + b[k];
            float hs = xn * sigf(xn);
            o[k] = (short)f2b(hs);
            srow8[k] += hs;
        }
        *(frag_ab*)dst = o;
    }
    #pragma unroll
    for (int k = 0; k < 8; k++) sred[jg * 256 + c8 + k] = srow8[k];
    __syncthreads();
    {
        const int c = t;
        float s = 0.f;
        #pragma unroll
        for (int k = 0; k < 8; k++) s += sred[k * 256 + c];
        Srow[(size_t)(n * HH + i) * CC + c] = s;
    }
}

// Scol[n][j][c] = sum_i hs[n][i*80+j][c].  Block (jg, iq, n); atomics (Scol pre-zeroed).
__global__ __launch_bounds__(256) void scol_kernel(
    const u16* __restrict__ hb, float* __restrict__ Scol)
{
    const int jg = blockIdx.x, iq = blockIdx.y, n = blockIdx.z;
    const int t = threadIdx.x;
    const int js = t >> 5, cc = t & 31;
    const int j = jg * 8 + js, c8 = cc * 8;
    float acc8[8];
    #pragma unroll
    for (int k = 0; k < 8; k++) acc8[k] = 0.f;
    for (int s = 0; s < 20; s++) {
        const int i = iq * 20 + s;
        frag_ab v = *(const frag_ab*)(hb + (size_t)(n * PP + i * WW + j) * CC + c8);
        #pragma unroll
        for (int k = 0; k < 8; k++) acc8[k] += b2f((u16)v[k]);
    }
    float* dst = Scol + (size_t)(n * HH + j) * CC + c8;
    #pragma unroll
    for (int k = 0; k < 8; k++) atomicAdd(&dst[k], acc8[k]);
}

// depthwise 3x3 zero-pad in [p][c] layout.  Block (i, chalf, n).
__global__ __launch_bounds__(256) void dw_kernel(
    const u16* __restrict__ gin, u16* __restrict__ dout,
    const float* __restrict__ wdw)
{
    __shared__ float sw[1152];   // 128 c * 9
    const int i = blockIdx.x, chalf = blockIdx.y, n = blockIdx.z;
    const int t = threadIdx.x;
    for (int u = t; u < 1152; u += 256) sw[u] = wdw[chalf * 1152 + u];
    __syncthreads();

    const int jg = t >> 5, cc = t & 31;
    const int gc = chalf * 128 + cc * 4;   // global c of 4-chunk
    float wl[4][9];
    #pragma unroll
    for (int cl = 0; cl < 4; cl++)
        #pragma unroll
        for (int k = 0; k < 9; k++) wl[cl][k] = sw[(cc * 4 + cl) * 9 + k];

    const size_t nbase = (size_t)n * PP * CC;
    for (int s = 0; s < 10; s++) {
        const int j = jg + s * 8;
        float acc4[4] = {0.f, 0.f, 0.f, 0.f};
        #pragma unroll
        for (int di = -1; di <= 1; di++) {
            const int ii = i + di;
            if (ii < 0 || ii >= HH) continue;
            #pragma unroll
            for (int dj = -1; dj <= 1; dj++) {
                const int jj = j + dj;
                if (jj < 0 || jj >= WW) continue;
                ushort4 v = *(const ushort4*)(gin + nbase + (size_t)(ii * WW + jj) * CC + gc);
                const int k = (di + 1) * 3 + (dj + 1);
                acc4[0] += wl[0][k] * b2f(v.x);
                acc4[1] += wl[1][k] * b2f(v.y);
                acc4[2] += wl[2][k] * b2f(v.z);
                acc4[3] += wl[3][k] * b2f(v.w);
            }
        }
        ushort4 o;
        o.x = f2b(acc4[0]); o.y = f2b(acc4[1]); o.z = f2b(acc4[2]); o.w = f2b(acc4[3]);
        *(ushort4*)(dout + nbase + (size_t)(i * WW + j) * CC + gc) = o;
    }
}

// GN2 + SiLU + transpose-out: Y [n][p][c] bf16 -> out [n][c][p] fp32.  64p x 64c tile.
__global__ __launch_bounds__(256) void gn2T_kernel(
    const u16* __restrict__ Y, float* __restrict__ out,
    const float* __restrict__ stats,
    const float* __restrict__ g2, const float* __restrict__ b2v)
{
    __shared__ u16 sT[64 * 72];
    const int p0 = blockIdx.x * 64, c0 = blockIdx.y * 64, n = blockIdx.z;
    const int t = threadIdx.x;
    {   // phase 1: read Y rows (coalesced along c)
        const int pl = t >> 2, cq = t & 3;
        const u16* row = Y + (size_t)(n * PP + p0 + pl) * CC + c0 + cq * 16;
        *(frag_ab*)(sT + pl * 72 + cq * 16)     = *(const frag_ab*)(row);
        *(frag_ab*)(sT + pl * 72 + cq * 16 + 8) = *(const frag_ab*)(row + 8);
    }
    __syncthreads();
    {   // phase 2: per-c affine + silu, write out rows (coalesced along p)
        const int cl = t >> 2, pq = t & 3;
        const int c = c0 + cl, g = c >> 4;
        const float su   = stats[256 + n * GG + g];
        const float sq   = stats[384 + n * GG + g];
        const float mean = su * (1.f / GNCNT);
        const float var  = sq * (1.f / GNCNT) - mean * mean;
        const float inv  = rsqrtf(var + 1e-5f);
        const float a    = inv * g2[c];
        const float b    = b2v[c] - mean * a;
        float* orow = out + (size_t)(n * CC + c) * PP + p0 + pq * 16;
        #pragma unroll
        for (int u4 = 0; u4 < 4; u4++) {
            float4 o;
            float* op = (float*)&o;
            #pragma unroll
            for (int e = 0; e < 4; e++) {
                const int pp = pq * 16 + u4 * 4 + e;
                float xn = b2f(sT[pp * 72 + cl]) * a + b;
                op[e] = xn * sigf(xn);
            }
            ((float4*)(orow + u4 * 4))[0] = o;
        }
    }
}

extern "C" void kernel_launch(void* const* d_in, const int* in_sizes, int n_in,
                              void* d_out, int out_size, void* d_ws, size_t ws_size,
                              hipStream_t stream)
{
    const float* x      = (const float*)d_in[0];
    const float* w_pre  = (const float*)d_in[1];
    const float* g1     = (const float*)d_in[2];
    const float* b1     = (const float*)d_in[3];
    const float* w_gate = (const float*)d_in[4];
    const float* b_gate = (const float*)d_in[5];
    const float* w_dw   = (const float*)d_in[6];
    const float* w_pw   = (const float*)d_in[7];
    const float* g2     = (const float*)d_in[8];
    const float* b2     = (const float*)d_in[9];
    float* out = (float*)d_out;

    char* ws = (char*)d_ws;
    u16*   wb0   = (u16*)(ws);                      // 131,072 B
    u16*   wb1   = (u16*)(ws + 131072);             // 131,072 B
    u16*   wb2   = (u16*)(ws + 262144);             // 131,072 B
    u16*   Xt    = (u16*)(ws + 393216);             // 26,214,400 B
    u16*   bufA  = (u16*)(ws + 26607616);           // 26,214,400 B
    u16*   bufB  = (u16*)(ws + 52822016);           // 26,214,400 B
    float* Srow  = (float*)(ws + 79036416);         // 655,360 B
    float* Scol  = (float*)(ws + 79691776);         // 655,360 B
    float* stats = (float*)(ws + 80347136);         // 2,048 B

    hipMemsetAsync(stats, 0, 2048, stream);
    hipMemsetAsync(Scol, 0, 655360, stream);

    cvt_kernel<<<64, 256, 0, stream>>>(w_pre,  wb0, 16384);
    cvt_kernel<<<64, 256, 0, stream>>>(w_gate, wb1, 16384);
    cvt_kernel<<<64, 256, 0, stream>>>(w_pw,   wb2, 16384);
    cvtT_kernel<<<dim3(100, 4, 8), 256, 0, stream>>>(x, Xt);

    dim3 ggrid(400, 4);   // m-tiles(128) x o-tiles(64); same-A o-repeats stay on one XCD
    // conv1 + GN1 stats
    gemm_kernel<0><<<ggrid, 256, 0, stream>>>(Xt, wb0, bufA, stats,
                                              nullptr, nullptr, nullptr, nullptr);
    // GN1 + SiLU + Srow
    gn1_kernel<<<dim3(80, 8), 256, 0, stream>>>(bufA, bufB, Srow, stats, g1, b1);
    // Scol
    scol_kernel<<<dim3(10, 4, 8), 256, 0, stream>>>(bufB, Scol);
    // gate conv + fused-scan gating
    gemm_kernel<1><<<ggrid, 256, 0, stream>>>(bufB, wb1, bufA, stats,
                                              bufB, Srow, Scol, b_gate);
    // depthwise 3x3
    dw_kernel<<<dim3(80, 2, 8), 256, 0, stream>>>(bufA, bufB, w_dw);
    // conv3 + GN2 stats
    gemm_kernel<2><<<ggrid, 256, 0, stream>>>(bufB, wb2, bufA, stats,
                                              nullptr, nullptr, nullptr, nullptr);
    // GN2 + SiLU -> fp32 out (transposed)
    gn2T_kernel<<<dim3(100, 4, 8), 256, 0, stream>>>(bufA, out, stats, g2, b2);
}